// Round 4
// baseline (879.410 us; speedup 1.0000x reference)
//
#include <hip/hip_runtime.h>
#include <hip/hip_bf16.h>
#include <stdint.h>

typedef unsigned int u32;
typedef unsigned long long u64;

typedef short bf16x8 __attribute__((ext_vector_type(8)));
typedef float f32x4 __attribute__((ext_vector_type(4)));

// Problem constants: B=32, D=1024, N=65536, K=4096, H=8, hd=128
// Inputs fp32; internal GEMM compute bf16 MFMA (verified within tolerance R3).

__device__ __forceinline__ float bf2f(uint16_t x) {
    return __uint_as_float(((u32)x) << 16);
}
__device__ __forceinline__ uint16_t f2bf(float f) {
    u32 u = __float_as_uint(f);
    u32 r = (u + 0x7FFF + ((u >> 16) & 1)) >> 16;
    return (uint16_t)r;
}
__device__ __forceinline__ u32 prio_to_ds(float p) {
    // descending-sortable transform: ascending ds == descending priority
    u32 fb = __float_as_uint(p);
    u32 s = (fb & 0x80000000u) ? ~fb : (fb | 0x80000000u);
    return ~s;
}

// ---------------- top-k via radix-select + small sort ----------------
// 1) 13-bit histogram of ds  2) scan -> threshold bucket B  3) compact buckets<=B
// 4) single-block bitonic sort of 8192 (sentinel-padded) -> first 4096 = answer.
// Matches jax.lax.top_k semantics (desc value, ties by asc index) exactly.

__global__ void zero_hist_kernel(u32* __restrict__ hist, u32* __restrict__ counter) {
    int i = blockIdx.x * 256 + threadIdx.x; // 8192
    hist[i] = 0;
    if (i == 0) counter[0] = 0;
}

__global__ __launch_bounds__(256) void hist_kernel(const float* __restrict__ prio,
                                                   u32* __restrict__ hist) {
    __shared__ u32 lh[8192];
    int t = threadIdx.x;
    for (int s = t; s < 8192; s += 256) lh[s] = 0;
    __syncthreads();
    int i = blockIdx.x * 256 + t; // 65536
    u32 ds = prio_to_ds(prio[i]);
    atomicAdd(&lh[ds >> 19], 1u);
    __syncthreads();
    for (int s = t; s < 8192; s += 256)
        if (lh[s]) atomicAdd(&hist[s], lh[s]);
}

__global__ __launch_bounds__(1024) void scan_setup_kernel(const u32* __restrict__ hist,
                                                          int* __restrict__ selinfo,
                                                          u64* __restrict__ comp) {
    __shared__ u32 psum[1024];
    int t = threadIdx.x;
    u32 loc[8];
    u32 s = 0;
#pragma unroll
    for (int j = 0; j < 8; ++j) { loc[j] = hist[t * 8 + j]; s += loc[j]; }
    psum[t] = s;
    __syncthreads();
    for (int off = 1; off < 1024; off <<= 1) {
        u32 v = (t >= off) ? psum[t - off] : 0;
        __syncthreads();
        psum[t] += v;
        __syncthreads();
    }
    u32 cum = psum[t] - s; // exclusive prefix
#pragma unroll
    for (int j = 0; j < 8; ++j) {
        u32 c = loc[j];
        if (cum <= 4095u && 4095u < cum + c) { selinfo[0] = t * 8 + j; }
        cum += c;
    }
    // sentinel-pad compact buffer (sorts to the end)
#pragma unroll
    for (int j = 0; j < 8; ++j) comp[t * 8 + j] = ~0ull;
}

__global__ void compact_kernel(const float* __restrict__ prio,
                               const int* __restrict__ selinfo,
                               u64* __restrict__ comp,
                               u32* __restrict__ counter) {
    int i = blockIdx.x * 256 + threadIdx.x; // 65536
    u32 ds = prio_to_ds(prio[i]);
    if ((int)(ds >> 19) <= selinfo[0]) {
        u32 pos = atomicAdd(counter, 1u);
        if (pos < 8192u) comp[pos] = ((u64)ds << 32) | (u64)i;
    }
}

__global__ __launch_bounds__(1024) void sort8192_kernel(const u64* __restrict__ comp,
                                                        int* __restrict__ idx) {
    __shared__ u64 sh[8192]; // 64 KB exactly
    int t = threadIdx.x;
#pragma unroll
    for (int j = 0; j < 8; ++j) sh[t + j * 1024] = comp[t + j * 1024];
    __syncthreads();
    for (int k = 2; k <= 8192; k <<= 1) {
        for (int j = k >> 1; j >= 1; j >>= 1) {
#pragma unroll
            for (int pp = 0; pp < 4; ++pp) {
                int p = t + pp * 1024; // 4096 pairs
                int i1 = ((p & ~(j - 1)) << 1) | (p & (j - 1));
                int i2 = i1 | j;
                bool up = ((i1 & k) == 0);
                u64 a = sh[i1], b = sh[i2];
                if ((a > b) == up) { sh[i1] = b; sh[i2] = a; }
            }
            __syncthreads();
        }
    }
#pragma unroll
    for (int j = 0; j < 4; ++j) idx[t + j * 1024] = (int)(u32)(sh[t + j * 1024] & 0xFFFFFFFFull);
}

// ---------------- gather selected buffer rows, fp32 -> bf16 ----------------
__global__ __launch_bounds__(256) void gather_convert_kernel(const float* __restrict__ buffer,
                                                             const int* __restrict__ idx,
                                                             uint16_t* __restrict__ bsub) {
    int row = blockIdx.x;          // 4096 rows
    int c4 = threadIdx.x * 4;      // 256 threads x 4 floats = 1024
    const float* src = buffer + (size_t)idx[row] * 1024 + c4;
    float4 v = *(const float4*)src;
    ushort4 r;
    r.x = f2bf(v.x); r.y = f2bf(v.y); r.z = f2bf(v.z); r.w = f2bf(v.w);
    *(ushort4*)(bsub + (size_t)row * 1024 + c4) = r;
}

// ---------------- transpose Wk/Wv (fp32 -> bf16) for GEMM B-fragments ----------------
__global__ __launch_bounds__(256) void transpose_kernel(const float* __restrict__ Wk,
                                                        const float* __restrict__ Wv,
                                                        uint16_t* __restrict__ WkT,
                                                        uint16_t* __restrict__ WvT) {
    int tx = blockIdx.x, ty = blockIdx.y, m = blockIdx.z;
    const float* src = m ? Wv : Wk;
    uint16_t* dst = m ? WvT : WkT;
    __shared__ uint16_t tile[64][65];
    int t = threadIdx.x;
    for (int s = t; s < 4096; s += 256) {
        int r = s >> 6, c = s & 63;
        tile[r][c] = f2bf(src[(size_t)(ty * 64 + r) * 1024 + tx * 64 + c]);
    }
    __syncthreads();
    for (int s = t; s < 4096; s += 256) {
        int r = s >> 6, c = s & 63;
        dst[(size_t)(tx * 64 + r) * 1024 + ty * 64 + c] = tile[c][r];
    }
}

// ---------------- q projection: q = query @ Wq + bq (pure fp32) ----------------
__global__ __launch_bounds__(256) void qproj_kernel(const float* __restrict__ X,
                                                    const float* __restrict__ W,
                                                    const float* __restrict__ bias,
                                                    float* __restrict__ out) {
    int b = blockIdx.x, nc = blockIdx.y, t = threadIdx.x;
    __shared__ float xs[1024];
    for (int s = t; s < 1024; s += 256) xs[s] = X[b * 1024 + s];
    __syncthreads();
    int n = nc * 256 + t;
    float acc = bias[n];
#pragma unroll 4
    for (int k = 0; k < 1024; ++k) acc += xs[k] * W[(size_t)k * 1024 + n];
    out[b * 1024 + n] = acc;
}

// ---------------- gathered K/V projection GEMM (MFMA bf16), bf16 output ----------------
__global__ __launch_bounds__(256) void kv_gemm_kernel(const uint16_t* __restrict__ bsub,
                                                      const uint16_t* __restrict__ WT0,
                                                      const uint16_t* __restrict__ WT1,
                                                      const float* __restrict__ b0,
                                                      const float* __restrict__ b1,
                                                      uint16_t* __restrict__ out0,
                                                      uint16_t* __restrict__ out1) {
    const int nt = blockIdx.x, mt = blockIdx.y, mat = blockIdx.z;
    const uint16_t* WT = mat ? WT1 : WT0;
    const float* bias = mat ? b1 : b0;
    uint16_t* out = mat ? out1 : out0;

    __shared__ __align__(16) uint16_t As[128 * 64];
    __shared__ __align__(16) uint16_t Bs[128 * 64];

    const int t = threadIdx.x;
    const int lane = t & 63;
    const int w = t >> 6;
    const int wm = (w >> 1) * 64, wn = (w & 1) * 64;
    const int q16 = lane >> 4;
    const int l15 = lane & 15;

    f32x4 acc[4][4];
#pragma unroll
    for (int i = 0; i < 4; i++)
#pragma unroll
        for (int j = 0; j < 4; j++) acc[i][j] = (f32x4){0.f, 0.f, 0.f, 0.f};

    const int sr = t >> 3;
    const int sc = t & 7;

    for (int kk = 0; kk < 1024; kk += 64) {
#pragma unroll
        for (int p = 0; p < 4; ++p) {
            int r = p * 32 + sr;
            int pc = sc ^ (r & 7);
            uint4 va = *(const uint4*)(bsub + (size_t)(mt * 128 + r) * 1024 + kk + sc * 8);
            uint4 vb = *(const uint4*)(WT + (size_t)(nt * 128 + r) * 1024 + kk + sc * 8);
            *(uint4*)&As[r * 64 + pc * 8] = va;
            *(uint4*)&Bs[r * 64 + pc * 8] = vb;
        }
        __syncthreads();
#pragma unroll
        for (int f = 0; f < 2; ++f) {
            bf16x8 a[4], b[4];
#pragma unroll
            for (int i = 0; i < 4; ++i) {
                int m = wm + i * 16 + l15;
                int pc = (f * 4 + q16) ^ (m & 7);
                a[i] = *(const bf16x8*)&As[m * 64 + pc * 8];
                int n = wn + i * 16 + l15;
                b[i] = *(const bf16x8*)&Bs[n * 64 + pc * 8];
            }
#pragma unroll
            for (int i = 0; i < 4; ++i)
#pragma unroll
                for (int j = 0; j < 4; ++j)
                    acc[i][j] = __builtin_amdgcn_mfma_f32_16x16x32_bf16(a[i], b[j], acc[i][j], 0, 0, 0);
        }
        __syncthreads();
    }

#pragma unroll
    for (int j = 0; j < 4; ++j) {
        int n = nt * 128 + wn + j * 16 + l15;
        float bn = bias[n];
#pragma unroll
        for (int i = 0; i < 4; ++i) {
            int m0 = mt * 128 + wm + i * 16 + q16 * 4;
#pragma unroll
            for (int r = 0; r < 4; ++r)
                out[(size_t)(m0 + r) * 1024 + n] = f2bf(acc[i][j][r] + bn);
        }
    }
}

// ---------------- fused attention: scores -> softmax -> attn row + ctx ----------------
__global__ __launch_bounds__(256) void attn_fused_kernel(const float* __restrict__ qp,
                                                         const uint16_t* __restrict__ ksub,
                                                         const uint16_t* __restrict__ vsub,
                                                         float* __restrict__ attn,
                                                         float* __restrict__ ctx) {
    int b = blockIdx.x, h = blockIdx.y, t = threadIdx.x;
    __shared__ float qsh[128];
    __shared__ float ssh[4096];
    __shared__ float red[8];
    __shared__ float red2[128];
    if (t < 128) qsh[t] = qp[b * 1024 + h * 128 + t];
    __syncthreads();
    // scores
    for (int kk = t; kk < 4096; kk += 256) {
        const uint16_t* kr = ksub + (size_t)kk * 1024 + h * 128;
        float acc = 0.f;
#pragma unroll
        for (int d8 = 0; d8 < 128; d8 += 8) {
            uint4 p = *(const uint4*)(kr + d8);
            acc += bf2f((uint16_t)p.x) * qsh[d8 + 0];
            acc += bf2f((uint16_t)(p.x >> 16)) * qsh[d8 + 1];
            acc += bf2f((uint16_t)p.y) * qsh[d8 + 2];
            acc += bf2f((uint16_t)(p.y >> 16)) * qsh[d8 + 3];
            acc += bf2f((uint16_t)p.z) * qsh[d8 + 4];
            acc += bf2f((uint16_t)(p.z >> 16)) * qsh[d8 + 5];
            acc += bf2f((uint16_t)p.w) * qsh[d8 + 6];
            acc += bf2f((uint16_t)(p.w >> 16)) * qsh[d8 + 7];
        }
        ssh[kk] = acc * 0.08838834764831845f;
    }
    __syncthreads();
    // softmax
    float m = -1e30f;
    for (int i = t; i < 4096; i += 256) m = fmaxf(m, ssh[i]);
#pragma unroll
    for (int o = 32; o >= 1; o >>= 1) m = fmaxf(m, __shfl_xor(m, o));
    if ((t & 63) == 0) red[t >> 6] = m;
    __syncthreads();
    m = fmaxf(fmaxf(red[0], red[1]), fmaxf(red[2], red[3]));
    float sum = 0.f;
    for (int i = t; i < 4096; i += 256) {
        float e = __expf(ssh[i] - m);
        ssh[i] = e;
        sum += e;
    }
#pragma unroll
    for (int o = 32; o >= 1; o >>= 1) sum += __shfl_xor(sum, o);
    if ((t & 63) == 0) red[4 + (t >> 6)] = sum;
    __syncthreads();
    sum = red[4] + red[5] + red[6] + red[7];
    float inv = 1.f / sum;
    float* arow = attn + (size_t)(b * 8 + h) * 4096;
    for (int i = t; i < 4096; i += 256) {
        float a = ssh[i] * inv;
        ssh[i] = a;
        arow[i] = a;
    }
    __syncthreads();
    // ctx = attn . v
    int d = t & 127, half = t >> 7;
    float acc = 0.f;
    const uint16_t* vbase = vsub + h * 128 + d;
    int k0 = half * 2048;
#pragma unroll 4
    for (int k = k0; k < k0 + 2048; ++k) acc += ssh[k] * bf2f(vbase[(size_t)k * 1024]);
    if (half) red2[d] = acc;
    __syncthreads();
    if (!half) ctx[b * 1024 + h * 128 + d] = acc + red2[d];
}

// ---------------- attn_avg = mean over heads -> fp32 out ----------------
__global__ void attn_avg_kernel(const float* __restrict__ attn, float* __restrict__ out) {
    int g = blockIdx.x * 256 + threadIdx.x; // 131072
    int b = g >> 12, k = g & 4095;
    float s = 0.f;
#pragma unroll
    for (int h = 0; h < 8; ++h) s += attn[(size_t)(b * 8 + h) * 4096 + k];
    out[g] = s * 0.125f;
}

// ---------------- output projection: retrieved = ctx @ Wo + bo (pure fp32) ----------------
__global__ __launch_bounds__(256) void outproj_kernel(const float* __restrict__ ctx,
                                                      const float* __restrict__ W,
                                                      const float* __restrict__ bias,
                                                      float* __restrict__ out) {
    int b = blockIdx.x, nc = blockIdx.y, t = threadIdx.x;
    __shared__ float xs[1024];
    for (int s = t; s < 1024; s += 256) xs[s] = ctx[b * 1024 + s];
    __syncthreads();
    int n = nc * 256 + t;
    float acc = bias[n];
#pragma unroll 4
    for (int k = 0; k < 1024; ++k) acc += xs[k] * W[(size_t)k * 1024 + n];
    out[b * 1024 + n] = acc;
}

extern "C" void kernel_launch(void* const* d_in, const int* in_sizes, int n_in,
                              void* d_out, int out_size, void* d_ws, size_t ws_size,
                              hipStream_t stream) {
    const float* query  = (const float*)d_in[0];
    const float* buffer = (const float*)d_in[1];
    const float* prio   = (const float*)d_in[2];
    const float* Wq     = (const float*)d_in[3];
    const float* bq     = (const float*)d_in[4];
    const float* Wk     = (const float*)d_in[5];
    const float* bk     = (const float*)d_in[6];
    const float* Wv     = (const float*)d_in[7];
    const float* bv     = (const float*)d_in[8];
    const float* Wo     = (const float*)d_in[9];
    const float* bo     = (const float*)d_in[10];

    char* w = (char*)d_ws;
    auto alloc = [&](size_t bytes) {
        char* p = w;
        w += (bytes + 255) & ~(size_t)255;
        return p;
    };
    u32* hist      = (u32*)alloc((size_t)8192 * 4);             // 32 KB
    u32* counter   = (u32*)alloc(256);
    int* selinfo   = (int*)alloc(256);
    u64* comp      = (u64*)alloc((size_t)8192 * 8);             // 64 KB
    int* idx       = (int*)alloc((size_t)4096 * 4);             // 16 KB
    uint16_t* WkT  = (uint16_t*)alloc((size_t)1024 * 1024 * 2); // 2 MB
    uint16_t* WvT  = (uint16_t*)alloc((size_t)1024 * 1024 * 2); // 2 MB
    float* qp      = (float*)alloc((size_t)32 * 1024 * 4);      // 128 KB
    uint16_t* ksub = (uint16_t*)alloc((size_t)4096 * 1024 * 2); // 8 MB
    uint16_t* vsub = (uint16_t*)alloc((size_t)4096 * 1024 * 2); // 8 MB
    uint16_t* bsub = (uint16_t*)alloc((size_t)4096 * 1024 * 2); // 8 MB (reused as attn)
    float* ctx     = (float*)alloc((size_t)32 * 1024 * 4);      // 128 KB
    float* attn    = (float*)bsub; // alias; bsub dead after kv_gemm

    float* out_retrieved = (float*)d_out;         // [32,1024]
    float* out_attnavg   = (float*)d_out + 32768; // [32,4096]

    // 1. top-k (radix-select + single-block sort): 5 launches vs 23
    zero_hist_kernel<<<32, 256, 0, stream>>>(hist, counter);
    hist_kernel<<<256, 256, 0, stream>>>(prio, hist);
    scan_setup_kernel<<<1, 1024, 0, stream>>>(hist, selinfo, comp);
    compact_kernel<<<256, 256, 0, stream>>>(prio, selinfo, comp, counter);
    sort8192_kernel<<<1, 1024, 0, stream>>>(comp, idx);

    // 2. gather + convert, weight transposes, q projection
    gather_convert_kernel<<<4096, 256, 0, stream>>>(buffer, idx, bsub);
    transpose_kernel<<<dim3(16, 16, 2), 256, 0, stream>>>(Wk, Wv, WkT, WvT);
    qproj_kernel<<<dim3(32, 4), 256, 0, stream>>>(query, Wq, bq, qp);

    // 3. K/V projection GEMMs (MFMA bf16)
    kv_gemm_kernel<<<dim3(8, 32, 2), 256, 0, stream>>>(bsub, WkT, WvT, bk, bv, ksub, vsub);

    // 4. fused attention (scores+softmax+ctx) + head-average
    attn_fused_kernel<<<dim3(32, 8), 256, 0, stream>>>(qp, ksub, vsub, attn, ctx);
    attn_avg_kernel<<<512, 256, 0, stream>>>(attn, out_attnavg);

    // 5. output projection
    outproj_kernel<<<dim3(32, 4), 256, 0, stream>>>(ctx, Wo, bo, out_retrieved);
}